// Round 10
// baseline (278.531 us; speedup 1.0000x reference)
//
#include <hip/hip_runtime.h>
#include <hip/hip_bf16.h>
#include <math.h>

// MKAFullAttention: B=4, T=1024, D=1024, H=16, DH=64, BETA=0.9
// Round 10: attn = swapped-operand (R9 math) + pair-sum order (R8, fixes FETCH
//           regression) + pipelined 2-phase staging: unit=(tile,stream),
//           double-buffered 16KB LDS units, issue-K/loads -> compute -> V
//           ds_write -> single barrier. GEMMs unchanged from R9.
//   - l3 stream analytic: attend(l3) = broadcast(l3@wv).

#define B_ 4
#define T_ 1024
#define D_ 1024
#define H_ 16
#define DH_ 64
#define M_ 4096

#define ECH 64
#define NCH 16

typedef __attribute__((ext_vector_type(8))) short bf16x8;
typedef __attribute__((ext_vector_type(4))) short s16x4;
typedef __attribute__((ext_vector_type(4))) float f32x4;
typedef __attribute__((ext_vector_type(4))) unsigned int u32x4;

__device__ inline short f2b(float f) {
  __hip_bfloat16 h = __float2bfloat16(f);
  return *reinterpret_cast<short*>(&h);
}

__device__ inline unsigned int pack2(float lo, float hi) {
  return ((unsigned int)(unsigned short)f2b(hi) << 16) |
         (unsigned int)(unsigned short)f2b(lo);
}

__device__ inline void gload_lds16(const short* g, short* l) {
  __builtin_amdgcn_global_load_lds(
      (const __attribute__((address_space(1))) unsigned int*)g,
      (__attribute__((address_space(3))) unsigned int*)l, 16, 0, 0);
}

// ---------------- EMA chunked scan (+ fused x->bf16 convert) ----------------
__global__ __launch_bounds__(256) void ema_chunk_kernel(const float* __restrict__ x,
                                                        float* __restrict__ l2,
                                                        short* __restrict__ xb) {
  int idx = blockIdx.x * 256 + threadIdx.x;  // B*NCH*D = 65536
  int d = idx & (D_ - 1);
  int ch = (idx >> 10) & (NCH - 1);
  int b = idx >> 14;
  const float* xp = x + (size_t)(b * T_ + ch * ECH) * D_ + d;
  float* yp = l2 + (size_t)(b * T_ + ch * ECH) * D_ + d;
  short* xbp = xb + (size_t)(b * T_ + ch * ECH) * D_ + d;
  float y = 0.f;
#pragma unroll 4
  for (int t = 0; t < ECH; ++t) {
    float xv = xp[t * D_];
    y = 0.9f * y + 0.1f * xv;
    yp[t * D_] = y;
    xbp[t * D_] = f2b(xv);
  }
}

__global__ __launch_bounds__(256) void ema_carry_kernel(const float* __restrict__ l2,
                                                        float* __restrict__ g) {
  int idx = blockIdx.x * 256 + threadIdx.x;  // B*D = 4096
  int d = idx & (D_ - 1);
  int b = idx >> 10;
  const float b64 = 0.0011790184577739f;  // 0.9^64
  float G = 0.f;
  for (int ch = 0; ch < NCH; ++ch) {
    g[(size_t)(b * NCH + ch) * D_ + d] = G;
    float lf = l2[(size_t)(b * T_ + ch * ECH + ECH - 1) * D_ + d];
    G = lf + b64 * G;
  }
}

__global__ __launch_bounds__(256) void ema_fix_kernel(const float* __restrict__ l2,
                                                      const float* __restrict__ g,
                                                      short* __restrict__ l2b) {
  int idx = blockIdx.x * 256 + threadIdx.x;  // 4M
  int d = idx & (D_ - 1);
  int t = (idx >> 10) & (T_ - 1);
  int b = idx >> 20;
  int ch = t >> 6;
  int off = t & (ECH - 1);
  float G = g[(size_t)(b * NCH + ch) * D_ + d];
  float p9 = exp2f((float)(off + 1) * -0.15200309344504997f);  // 0.9^(off+1)
  l2b[idx] = f2b(l2[idx] + p9 * G);
}

// ---------------- weight transpose + convert: Wt[n][k] = bf16(W[k][n]) ----------------
__global__ __launch_bounds__(256) void transpose_w_kernel(
    const float* __restrict__ w0, const float* __restrict__ w1,
    const float* __restrict__ w2, const float* __restrict__ w3,
    const float* __restrict__ w4,
    short* __restrict__ t0, short* __restrict__ t1, short* __restrict__ t2,
    short* __restrict__ t3, short* __restrict__ t4) {
  int z = blockIdx.z;
  const float* W = (z == 0) ? w0 : (z == 1) ? w1 : (z == 2) ? w2 : (z == 3) ? w3 : w4;
  short* Wt = (z == 0) ? t0 : (z == 1) ? t1 : (z == 2) ? t2 : (z == 3) ? t3 : t4;
  int cols = (z == 4) ? 512 : 1024;
  int c0 = blockIdx.x * 32, r0 = blockIdx.y * 32;
  if (c0 >= cols) return;
  __shared__ float tile[32][33];
  int tc = threadIdx.x & 31, tr8 = threadIdx.x >> 5;
#pragma unroll
  for (int i = 0; i < 4; ++i)
    tile[tr8 + i * 8][tc] = W[(size_t)(r0 + tr8 + i * 8) * cols + c0 + tc];
  __syncthreads();
#pragma unroll
  for (int i = 0; i < 4; ++i) {
    int rr = tr8 + i * 8;
    Wt[(size_t)(c0 + rr) * 1024 + r0 + tc] = f2b(tile[tc][rr]);
  }
}

// ---------------- bf16 MFMA GEMM: C[M,N] = A[M,K](lda) @ Bt[N,K]^T ----------------
template <int NB>
__global__ __launch_bounds__(256) void gemm_bt(const short* __restrict__ A, int lda,
                                               const short* __restrict__ Bt,
                                               float* __restrict__ Cf,
                                               short* __restrict__ Cb,
                                               int Ndim, int Kdim) {
  __shared__ short As[128 * 64];
  __shared__ short Bs[NB * 64];
  constexpr int NW = NB / 64;
  constexpr int NF = 4;
  constexpr int MF = (NW == 2) ? 4 : 2;
  int tid = threadIdx.x;
  int w = tid >> 6, l = tid & 63;
  int lg = l >> 4, ll = l & 15;
  int wr = (NW == 2) ? (w >> 1) : w;
  int wc = (NW == 2) ? (w & 1) : 0;
  int row0 = blockIdx.y * 128, col0 = blockIdx.x * NB;

  f32x4 acc[MF][NF];
#pragma unroll
  for (int m = 0; m < MF; ++m)
#pragma unroll
    for (int n = 0; n < NF; ++n) acc[m][n] = (f32x4){0.f, 0.f, 0.f, 0.f};

  for (int k0 = 0; k0 < Kdim; k0 += 64) {
    __syncthreads();
#pragma unroll
    for (int it = 0; it < 4; ++it) {
      int s = it * 256 + w * 64 + l;
      int r = s >> 3;
      int c = (s & 7) ^ (r & 7);
      gload_lds16(A + (size_t)(row0 + r) * lda + k0 + c * 8, &As[(it * 256 + w * 64) * 8]);
    }
#pragma unroll
    for (int it = 0; it < NB / 32; ++it) {
      int s = it * 256 + w * 64 + l;
      int r = s >> 3;
      int c = (s & 7) ^ (r & 7);
      gload_lds16(Bt + (size_t)(col0 + r) * Kdim + k0 + c * 8, &Bs[(it * 256 + w * 64) * 8]);
    }
    __syncthreads();
#pragma unroll
    for (int ks = 0; ks < 2; ++ks) {
      bf16x8 af[MF], bfr[NF];
#pragma unroll
      for (int m = 0; m < MF; ++m) {
        int r = wr * (MF * 16) + m * 16 + ll;
        af[m] = *(const bf16x8*)&As[r * 64 + (((ks * 4 + lg) ^ (r & 7)) << 3)];
      }
#pragma unroll
      for (int n = 0; n < NF; ++n) {
        int r = wc * 64 + n * 16 + ll;
        bfr[n] = *(const bf16x8*)&Bs[r * 64 + (((ks * 4 + lg) ^ (r & 7)) << 3)];
      }
#pragma unroll
      for (int m = 0; m < MF; ++m)
#pragma unroll
        for (int n = 0; n < NF; ++n)
          acc[m][n] = __builtin_amdgcn_mfma_f32_16x16x32_bf16(af[m], bfr[n], acc[m][n], 0, 0, 0);
    }
  }
#pragma unroll
  for (int m = 0; m < MF; ++m) {
    int gr = row0 + wr * (MF * 16) + m * 16 + lg * 4;
#pragma unroll
    for (int n = 0; n < NF; ++n) {
      int gc = col0 + wc * 64 + n * 16 + ll;
#pragma unroll
      for (int r = 0; r < 4; ++r) {
        float vv = acc[m][n][r];
        if (Cf) Cf[(size_t)(gr + r) * Ndim + gc] = vv;
        if (Cb) Cb[(size_t)(gr + r) * Ndim + gc] = f2b(vv);
      }
    }
  }
}

// ---------------- merged QKV + KV2 GEMM (1280 blocks, XCD-chunked swizzle) ----------------
__global__ __launch_bounds__(256) void gemm_dual(const short* __restrict__ xb,
                                                 const short* __restrict__ l2b,
                                                 const short* __restrict__ wqkvT,
                                                 short* __restrict__ QKV,
                                                 short* __restrict__ KV2) {
  int lin = blockIdx.y * 40 + blockIdx.x;
  int lin2 = (lin & 7) * 160 + (lin >> 3);
  int bx = lin2 % 40;
  int by = lin2 / 40;

  const short* A;
  const short* Bt;
  short* Cb;
  int Ndim, col0;
  if (bx < 24) {
    A = xb; Bt = wqkvT; Cb = QKV; Ndim = 3072; col0 = bx * 128;
  } else {
    A = l2b; Bt = wqkvT + 1024 * 1024; Cb = KV2; Ndim = 2048; col0 = (bx - 24) * 128;
  }
  __shared__ short As[128 * 64];
  __shared__ short Bs[128 * 64];
  int tid = threadIdx.x;
  int w = tid >> 6, l = tid & 63;
  int lg = l >> 4, ll = l & 15;
  int wr = w >> 1, wc = w & 1;
  int row0 = by * 128;

  f32x4 acc[4][4];
#pragma unroll
  for (int m = 0; m < 4; ++m)
#pragma unroll
    for (int n = 0; n < 4; ++n) acc[m][n] = (f32x4){0.f, 0.f, 0.f, 0.f};

  for (int k0 = 0; k0 < 1024; k0 += 64) {
    __syncthreads();
#pragma unroll
    for (int it = 0; it < 4; ++it) {
      int s = it * 256 + w * 64 + l;
      int r = s >> 3;
      int c = (s & 7) ^ (r & 7);
      gload_lds16(A + (size_t)(row0 + r) * 1024 + k0 + c * 8, &As[(it * 256 + w * 64) * 8]);
      gload_lds16(Bt + (size_t)(col0 + r) * 1024 + k0 + c * 8, &Bs[(it * 256 + w * 64) * 8]);
    }
    __syncthreads();
#pragma unroll
    for (int ks = 0; ks < 2; ++ks) {
      bf16x8 af[4], bfr[4];
#pragma unroll
      for (int m = 0; m < 4; ++m) {
        int r = wr * 64 + m * 16 + ll;
        af[m] = *(const bf16x8*)&As[r * 64 + (((ks * 4 + lg) ^ (r & 7)) << 3)];
      }
#pragma unroll
      for (int n = 0; n < 4; ++n) {
        int r = wc * 64 + n * 16 + ll;
        bfr[n] = *(const bf16x8*)&Bs[r * 64 + (((ks * 4 + lg) ^ (r & 7)) << 3)];
      }
#pragma unroll
      for (int m = 0; m < 4; ++m)
#pragma unroll
        for (int n = 0; n < 4; ++n)
          acc[m][n] = __builtin_amdgcn_mfma_f32_16x16x32_bf16(af[m], bfr[n], acc[m][n], 0, 0, 0);
    }
  }
#pragma unroll
  for (int m = 0; m < 4; ++m) {
    int gr = row0 + wr * 64 + m * 16 + lg * 4;
#pragma unroll
    for (int n = 0; n < 4; ++n) {
      int gc = col0 + wc * 64 + n * 16 + ll;
#pragma unroll
      for (int r = 0; r < 4; ++r)
        Cb[(size_t)(gr + r) * Ndim + gc] = f2b(acc[m][n][r]);
    }
  }
}

// ---------------- v3 = l3_memory @ wv  ([B,1024], f32) ----------------
__global__ __launch_bounds__(256) void v3_kernel(const float* __restrict__ l3,
                                                 const float* __restrict__ wv,
                                                 float* __restrict__ v3) {
  int idx = blockIdx.x * 256 + threadIdx.x;  // B*D = 4096
  int b = idx >> 10;
  int col = idx & 1023;
  const float* xr = l3 + (size_t)b * D_;
  float acc = 0.f;
#pragma unroll 8
  for (int k = 0; k < D_; ++k) acc += xr[k] * wv[(size_t)k * D_ + col];
  v3[idx] = acc;
}

// ---------------- router ----------------
__global__ __launch_bounds__(256) void router_kernel(const float* __restrict__ hdnp,
                                                     const float* __restrict__ rb1,
                                                     const float* __restrict__ rw2,
                                                     const float* __restrict__ rb2,
                                                     float* __restrict__ lam) {
  int wave = (blockIdx.x * 256 + threadIdx.x) >> 6;
  int lane = threadIdx.x & 63;
  const float* hr = hdnp + (size_t)wave * 512;
  float s0 = 0.f, s1 = 0.f, s2 = 0.f;
#pragma unroll
  for (int u = 0; u < 8; ++u) {
    int hcol = u * 64 + lane;
    float vv = hr[hcol] + rb1[hcol];
    float gl = 0.5f * vv * (1.0f + erff(vv * 0.70710678118654752f));
    s0 += gl * rw2[hcol * 3 + 0];
    s1 += gl * rw2[hcol * 3 + 1];
    s2 += gl * rw2[hcol * 3 + 2];
  }
#pragma unroll
  for (int off = 32; off; off >>= 1) {
    s0 += __shfl_xor(s0, off);
    s1 += __shfl_xor(s1, off);
    s2 += __shfl_xor(s2, off);
  }
  if (lane == 0) {
    float a = s0 + rb2[0], bb = s1 + rb2[1], c = s2 + rb2[2];
    float m = fmaxf(fmaxf(a, bb), c);
    float e0 = expf(a - m), e1 = expf(bb - m), e2 = expf(c - m);
    float inv = 1.0f / (e0 + e1 + e2);
    lam[(size_t)wave * 3 + 0] = e0 * inv;
    lam[(size_t)wave * 3 + 1] = e1 * inv;
    lam[(size_t)wave * 3 + 2] = e2 * inv;
  }
}

// ---------------- fused dual-stream swapped-operand flash attention ----------------
// One block = 64 q-rows of one (b,h); 4 waves x 16 rows. Unit = (tile,stream),
// 2-phase pipeline: issue K gload_lds + V global->reg for unit u+1, compute
// unit u, ds_write V(u+1), one barrier. Double-buffered 16KB units (32KB LDS).
// Swapped mfma(K,Q)/mfma(V,P): per-lane m/l, 2-shfl max, in-register P redist.
// Pair-sum block order (halves pair qb j with 15-j).
__global__ __launch_bounds__(256) void attn_fused_kernel(
    const short* __restrict__ q, int ldq,
    const short* __restrict__ k1, const short* __restrict__ v1, int ld1,
    const short* __restrict__ k2, const short* __restrict__ v2, int ld2,
    const float* __restrict__ lam, const float* __restrict__ v3,
    short* __restrict__ mixedb) {
  __shared__ short Ks[2][64][64];   // [buf][key][dh], k8 XOR swizzle (linear dest)
  __shared__ short Vt[2][64][64];   // [buf][dh][key], dword XOR swizzle

  int bid = blockIdx.x;
  int half = bid >> 9, p = bid & 511;
  int bh = p & 63;
  int j = p >> 6;
  int qb = half ? (15 - j) : j;  // pair-sum: constant work per block pair
  int b = bh >> 4, h = bh & 15;
  int q0 = qb * 64;
  int tid = threadIdx.x;
  int w = tid >> 6, l = tid & 63;
  int lg = l >> 4, ll = l & 15;

  int qw0 = q0 + w * 16;
  bf16x8 qf[2];
  {
    const short* qr = q + (size_t)(b * T_ + qw0 + ll) * ldq + h * DH_;
    qf[0] = *(const bf16x8*)&qr[lg * 8];
    qf[1] = *(const bf16x8*)&qr[32 + lg * 8];
  }

  float m_[2];
  f32x4 o[2][4];
  f32x4 ol[2];
#pragma unroll
  for (int s = 0; s < 2; ++s) {
    m_[s] = -1e30f;
#pragma unroll
    for (int db = 0; db < 4; ++db) o[s][db] = (f32x4){0.f, 0.f, 0.f, 0.f};
    ol[s] = (f32x4){0.f, 0.f, 0.f, 0.f};
  }

  bf16x8 ones;
#pragma unroll
  for (int jj = 0; jj < 8; ++jj) ones[jj] = (short)0x3F80;  // 1.0bf16

  // P redistribution source lanes (fixed per lane)
  int se = ll + (((2 * lg) & 3) << 4);
  int so = ll + (((2 * lg + 1) & 3) << 4);
  bool hi = (lg >= 2);

  // staging thread roles
  int kp2 = tid >> 3, c8 = tid & 7;  // V: key-pair, dh-octet
  const float SC = 0.125f * 1.44269504f;  // scale * log2(e)

  int nu = (qb + 1) * 2;  // units: (tile,stream)

  // ---- prologue: stage unit 0 (t64=0, s=0) into buf 0 ----
  {
#pragma unroll
    for (int it = 0; it < 2; ++it) {
      int e = it * 256 + w * 64 + l;
      int r = e >> 3;
      int cs = (e & 7) ^ (r & 7);
      gload_lds16(k1 + (size_t)(b * T_ + r) * ld1 + h * DH_ + cs * 8,
                  (short*)Ks[0] + (it * 256 + w * 64) * 8);
    }
    size_t gi = (size_t)(b * T_ + kp2 * 2) * ld1 + h * DH_ + c8 * 8;
    bf16x8 va = *(const bf16x8*)&v1[gi];
    bf16x8 vb = *(const bf16x8*)&v1[gi + ld1];
    unsigned int* Vtd = (unsigned int*)Vt[0];
#pragma unroll
    for (int jj = 0; jj < 8; ++jj) {
      int dh = c8 * 8 + jj;
      int X = ((dh ^ (dh >> 3)) & 7) << 2;
      Vtd[dh * 32 + (kp2 ^ X)] =
          ((unsigned int)(unsigned short)va[jj]) |
          (((unsigned int)(unsigned short)vb[jj]) << 16);
    }
  }
  __syncthreads();

  for (int u = 0; u < nu; ++u) {
    int buf = u & 1, nbuf = buf ^ 1;
    int s = u & 1;
    int key0 = (u >> 1) * 64;
    bool have_next = (u + 1 < nu);

    // ---- phase 1: issue next unit's K gload_lds + V global->reg ----
    bf16x8 va, vb;
    if (have_next) {
      int ns = (u + 1) & 1;
      int nkey0 = ((u + 1) >> 1) * 64;
      const short* nkp = ns ? k2 : k1;
      const short* nvp = ns ? v2 : v1;
      int nld = ns ? ld2 : ld1;
#pragma unroll
      for (int it = 0; it < 2; ++it) {
        int e = it * 256 + w * 64 + l;
        int r = e >> 3;
        int cs = (e & 7) ^ (r & 7);
        gload_lds16(nkp + (size_t)(b * T_ + nkey0 + r) * nld + h * DH_ + cs * 8,
                    (short*)Ks[nbuf] + (it * 256 + w * 64) * 8);
      }
      size_t gi = (size_t)(b * T_ + nkey0 + kp2 * 2) * nld + h * DH_ + c8 * 8;
      va = *(const bf16x8*)&nvp[gi];
      vb = *(const bf16x8*)&nvp[gi + nld];
    }

    // ---- phase 2: compute unit u ----
    if (key0 <= qw0 + 15) {
      // QK^T swapped: c[kt] rows=keys, cols=q
      f32x4 c[4];
#pragma unroll
      for (int kt = 0; kt < 4; ++kt) c[kt] = (f32x4){0.f, 0.f, 0.f, 0.f};
      __builtin_amdgcn_s_setprio(1);
#pragma unroll
      for (int kt = 0; kt < 4; ++kt) {
        int kr = kt * 16 + ll;
        bf16x8 kfa = *(const bf16x8*)&Ks[buf][kr][((lg ^ (kr & 7)) << 3)];
        bf16x8 kfb = *(const bf16x8*)&Ks[buf][kr][(((4 + lg) ^ (kr & 7)) << 3)];
        c[kt] = __builtin_amdgcn_mfma_f32_16x16x32_bf16(kfa, qf[0], c[kt], 0, 0, 0);
        c[kt] = __builtin_amdgcn_mfma_f32_16x16x32_bf16(kfb, qf[1], c[kt], 0, 0, 0);
      }
      __builtin_amdgcn_s_setprio(0);

      // scores: S[q=ll][key=key0+16kt+4lg+r]
      float sv[16];
      int row = qw0 + ll;
      if (key0 + 63 <= qw0) {
#pragma unroll
        for (int kt = 0; kt < 4; ++kt)
#pragma unroll
          for (int r = 0; r < 4; ++r) sv[kt * 4 + r] = c[kt][r] * SC;
      } else {
#pragma unroll
        for (int kt = 0; kt < 4; ++kt)
#pragma unroll
          for (int r = 0; r < 4; ++r) {
            float t = c[kt][r] * SC;
            sv[kt * 4 + r] = (key0 + kt * 16 + lg * 4 + r > row) ? -1e30f : t;
          }
      }

      // per-lane row max + 2-shfl cross-lg reduce
      float mx = sv[0];
#pragma unroll
      for (int i = 1; i < 16; ++i) mx = fmaxf(mx, sv[i]);
      mx = fmaxf(mx, __shfl_xor(mx, 16));
      mx = fmaxf(mx, __shfl_xor(mx, 32));

      // defer-max rescale
      if (__any(mx > m_[s] + 8.f)) {
        float nm = fmaxf(m_[s], mx);
        float al = exp2f(m_[s] - nm);
        m_[s] = nm;
        ol[s] *= al;
#pragma unroll
        for (int db = 0; db < 4; ++db) o[s][db] *= al;
      }

      // P = exp2(sv - m), pack into dwords
      unsigned int pk[4][2];
#pragma unroll
      for (int kt = 0; kt < 4; ++kt) {
        float p0 = exp2f(sv[kt * 4 + 0] - m_[s]);
        float p1 = exp2f(sv[kt * 4 + 1] - m_[s]);
        float p2 = exp2f(sv[kt * 4 + 2] - m_[s]);
        float p3 = exp2f(sv[kt * 4 + 3] - m_[s]);
        pk[kt][0] = pack2(p0, p1);
        pk[kt][1] = pack2(p2, p3);
      }

      // redistribute P to B-frag layout + PV (swapped)
      const unsigned int* Vtd = (const unsigned int*)Vt[buf];
#pragma unroll
      for (int ks = 0; ks < 2; ++ks) {
        unsigned int a0 = __shfl(pk[2 * ks][0], se), b0 = __shfl(pk[2 * ks + 1][0], se);
        unsigned int a1 = __shfl(pk[2 * ks][1], se), b1 = __shfl(pk[2 * ks + 1][1], se);
        unsigned int a2 = __shfl(pk[2 * ks][0], so), b2 = __shfl(pk[2 * ks + 1][0], so);
        unsigned int a3 = __shfl(pk[2 * ks][1], so), b3 = __shfl(pk[2 * ks + 1][1], so);
        u32x4 pd = {hi ? b0 : a0, hi ? b1 : a1, hi ? b2 : a2, hi ? b3 : a3};
        bf16x8 pf = *(bf16x8*)&pd;
        __builtin_amdgcn_s_setprio(1);
        ol[s] = __builtin_amdgcn_mfma_f32_16x16x32_bf16(ones, pf, ol[s], 0, 0, 0);
#pragma unroll
        for (int db = 0; db < 4; ++db) {
          int dh = db * 16 + ll;
          int X = ((dh ^ (dh >> 3)) & 7) << 2;
          bf16x8 vf = *(const bf16x8*)&Vtd[dh * 32 + ((ks * 16 + lg * 4) ^ X)];
          o[s][db] = __builtin_amdgcn_mfma_f32_16x16x32_bf16(vf, pf, o[s][db], 0, 0, 0);
        }
        __builtin_amdgcn_s_setprio(0);
      }
    }

    // ---- phase 3: write staged V regs (waits only its own vmcnt) ----
    if (have_next) {
      unsigned int* Vtd = (unsigned int*)Vt[nbuf];
#pragma unroll
      for (int jj = 0; jj < 8; ++jj) {
        int dh = c8 * 8 + jj;
        int X = ((dh ^ (dh >> 3)) & 7) << 2;
        Vtd[dh * 32 + (kp2 ^ X)] =
            ((unsigned int)(unsigned short)va[jj]) |
            (((unsigned int)(unsigned short)vb[jj]) << 16);
      }
    }
    __syncthreads();
  }

  // ---- epilogue: per-lane row = qw0+ll; O[q][dh=db*16+4lg+r] b64 stores ----
  int grow = qw0 + ll;
  const float* lr = lam + (size_t)(b * T_ + grow) * 3;
  float w0 = lr[0] / ol[0][0];
  float w1 = lr[1] / ol[1][0];
  float w2 = lr[2];
#pragma unroll
  for (int db = 0; db < 4; ++db) {
    s16x4 pkv;
#pragma unroll
    for (int r = 0; r < 4; ++r) {
      int dcol = h * DH_ + db * 16 + lg * 4 + r;
      float val = w0 * o[0][db][r] + w1 * o[1][db][r] + w2 * v3[(b << 10) + dcol];
      pkv[r] = f2b(val);
    }
    *(s16x4*)&mixedb[(size_t)(b * T_ + grow) * D_ + h * DH_ + db * 16 + lg * 4] = pkv;
  }
}

extern "C" void kernel_launch(void* const* d_in, const int* in_sizes, int n_in,
                              void* d_out, int out_size, void* d_ws, size_t ws_size,
                              hipStream_t stream) {
  const float* x = (const float*)d_in[0];
  const float* l3m = (const float*)d_in[1];
  const float* wq = (const float*)d_in[2];
  const float* wk = (const float*)d_in[3];
  const float* wv = (const float*)d_in[4];
  const float* wo = (const float*)d_in[5];
  const float* rw1 = (const float*)d_in[6];
  const float* rb1 = (const float*)d_in[7];
  const float* rw2 = (const float*)d_in[8];
  const float* rb2 = (const float*)d_in[9];

  float* out = (float*)d_out;
  float* lam = out + (size_t)M_ * D_;  // output tail: [4096,3]

  float* ws = (float*)d_ws;
  float* l2 = ws;
  short* QKV = (short*)ws;              // [4096][3072] bf16
  float* hdnp = ws + 6291456;           // 2M floats (after 24MB R0)
  float* v3 = ws + 8388608;
  float* gbuf = ws + 8392704;
  short* sb = (short*)(ws + 8458240);
  short* xb = sb;                       // 4M shorts
  short* l2b = sb + 4194304;            // 4M
  short* KV2 = sb + 8388608;            // 8M: [4096][2048]
  short* mixedb = sb + 16777216;        // 4M
  short* wqkvT = sb + 20971520;         // 3M: [3072][1024]
  short* woT = sb + 24117248;           // 1M
  short* rw1T = sb + 25165824;          // 512K

  dim3 blk(256);

  // weight transpose+convert (wq|wk|wv concat)
  transpose_w_kernel<<<dim3(32, 32, 5), blk, 0, stream>>>(
      wq, wk, wv, wo, rw1,
      wqkvT, wqkvT + 1024 * 1024, wqkvT + 2048 * 1024, woT, rw1T);

  // EMA l2 -> l2b (bf16), fused x->xb convert
  ema_chunk_kernel<<<256, blk, 0, stream>>>(x, l2, xb);
  ema_carry_kernel<<<16, blk, 0, stream>>>(l2, gbuf);
  ema_fix_kernel<<<16384, blk, 0, stream>>>(l2, gbuf, l2b);

  // [q|k1|v1] = xb @ wqkvT^T (N=3072) and [k2|v2] = l2b @ [wk|wv]^T (N=2048)
  gemm_dual<<<dim3(40, 32), blk, 0, stream>>>(xb, l2b, wqkvT, QKV, KV2);

  // router: hdnp = q @ rw1T (q strided inside QKV)
  gemm_bt<64><<<dim3(8, 32), blk, 0, stream>>>(QKV, 3072, rw1T, hdnp, (short*)nullptr, 512, 1024);
  router_kernel<<<1024, blk, 0, stream>>>(hdnp, rb1, rw2, rb2, lam);

  // l3 value vector
  v3_kernel<<<16, blk, 0, stream>>>(l3m, wv, v3);

  // fused dual-stream attention -> mixedb (bf16)
  attn_fused_kernel<<<1024, blk, 0, stream>>>(QKV, 3072,
                                              QKV + 1024, QKV + 2048, 3072,
                                              KV2, KV2 + 1024, 2048,
                                              lam, v3, mixedb);

  // out = mixedb @ woT
  gemm_bt<64><<<dim3(16, 32), blk, 0, stream>>>(mixedb, 1024, woT, out, (short*)nullptr, 1024, 1024);
}

// Round 11
// 251.230 us; speedup vs baseline: 1.1087x; 1.1087x over previous
//
#include <hip/hip_runtime.h>
#include <hip/hip_bf16.h>
#include <math.h>

// MKAFullAttention: B=4, T=1024, D=1024, H=16, DH=64, BETA=0.9
// Round 11: revert attention to R8 (best measured, 74us — R9/R10 swapped/
//           pipelined variants both regressed). EMA rebalance ECH=16/NCH=64
//           (4x occupancy, 4x shorter serial chain in ema_chunk).
//           GEMMs: R9 versions (NF=4 fix, XCD swizzle on gemm_dual).
//   - l3 stream analytic: attend(l3) = broadcast(l3@wv).

#define B_ 4
#define T_ 1024
#define D_ 1024
#define H_ 16
#define DH_ 64
#define M_ 4096

#define ECH 16
#define NCH 64

typedef __attribute__((ext_vector_type(8))) short bf16x8;
typedef __attribute__((ext_vector_type(4))) short s16x4;
typedef __attribute__((ext_vector_type(4))) float f32x4;

__device__ inline short f2b(float f) {
  __hip_bfloat16 h = __float2bfloat16(f);
  return *reinterpret_cast<short*>(&h);
}

__device__ inline void gload_lds16(const short* g, short* l) {
  __builtin_amdgcn_global_load_lds(
      (const __attribute__((address_space(1))) unsigned int*)g,
      (__attribute__((address_space(3))) unsigned int*)l, 16, 0, 0);
}

// ---------------- EMA chunked scan (+ fused x->bf16 convert) ----------------
// ECH=16 steps/chunk, NCH=64 chunks: 262144 threads (4 waves/SIMD).
__global__ __launch_bounds__(256) void ema_chunk_kernel(const float* __restrict__ x,
                                                        float* __restrict__ l2,
                                                        short* __restrict__ xb) {
  int idx = blockIdx.x * 256 + threadIdx.x;  // B*NCH*D = 262144
  int d = idx & (D_ - 1);
  int ch = (idx >> 10) & (NCH - 1);
  int b = idx >> 16;
  const float* xp = x + (size_t)(b * T_ + ch * ECH) * D_ + d;
  float* yp = l2 + (size_t)(b * T_ + ch * ECH) * D_ + d;
  short* xbp = xb + (size_t)(b * T_ + ch * ECH) * D_ + d;
  float y = 0.f;
#pragma unroll 4
  for (int t = 0; t < ECH; ++t) {
    float xv = xp[t * D_];
    y = 0.9f * y + 0.1f * xv;
    yp[t * D_] = y;
    xbp[t * D_] = f2b(xv);
  }
}

__global__ __launch_bounds__(256) void ema_carry_kernel(const float* __restrict__ l2,
                                                        float* __restrict__ g) {
  int idx = blockIdx.x * 256 + threadIdx.x;  // B*D = 4096
  int d = idx & (D_ - 1);
  int b = idx >> 10;
  const float bE = 0.1853020188851841f;  // 0.9^16
  float G = 0.f;
  for (int ch = 0; ch < NCH; ++ch) {
    g[(size_t)(b * NCH + ch) * D_ + d] = G;
    float lf = l2[(size_t)(b * T_ + ch * ECH + ECH - 1) * D_ + d];
    G = lf + bE * G;
  }
}

__global__ __launch_bounds__(256) void ema_fix_kernel(const float* __restrict__ l2,
                                                      const float* __restrict__ g,
                                                      short* __restrict__ l2b) {
  int idx = blockIdx.x * 256 + threadIdx.x;  // 4M
  int d = idx & (D_ - 1);
  int t = (idx >> 10) & (T_ - 1);
  int b = idx >> 20;
  int ch = t / ECH;
  int off = t & (ECH - 1);
  float G = g[(size_t)(b * NCH + ch) * D_ + d];
  float p9 = exp2f((float)(off + 1) * -0.15200309344504997f);  // 0.9^(off+1)
  l2b[idx] = f2b(l2[idx] + p9 * G);
}

// ---------------- weight transpose + convert: Wt[n][k] = bf16(W[k][n]) ----------------
__global__ __launch_bounds__(256) void transpose_w_kernel(
    const float* __restrict__ w0, const float* __restrict__ w1,
    const float* __restrict__ w2, const float* __restrict__ w3,
    const float* __restrict__ w4,
    short* __restrict__ t0, short* __restrict__ t1, short* __restrict__ t2,
    short* __restrict__ t3, short* __restrict__ t4) {
  int z = blockIdx.z;
  const float* W = (z == 0) ? w0 : (z == 1) ? w1 : (z == 2) ? w2 : (z == 3) ? w3 : w4;
  short* Wt = (z == 0) ? t0 : (z == 1) ? t1 : (z == 2) ? t2 : (z == 3) ? t3 : t4;
  int cols = (z == 4) ? 512 : 1024;
  int c0 = blockIdx.x * 32, r0 = blockIdx.y * 32;
  if (c0 >= cols) return;
  __shared__ float tile[32][33];
  int tc = threadIdx.x & 31, tr8 = threadIdx.x >> 5;
#pragma unroll
  for (int i = 0; i < 4; ++i)
    tile[tr8 + i * 8][tc] = W[(size_t)(r0 + tr8 + i * 8) * cols + c0 + tc];
  __syncthreads();
#pragma unroll
  for (int i = 0; i < 4; ++i) {
    int rr = tr8 + i * 8;
    Wt[(size_t)(c0 + rr) * 1024 + r0 + tc] = f2b(tile[tc][rr]);
  }
}

// ---------------- bf16 MFMA GEMM: C[M,N] = A[M,K](lda) @ Bt[N,K]^T ----------------
// 128xNB tile (NB=128 or 64), BK=64, 4 waves, global_load_lds 16B, XOR k8-swizzle.
// Per-wave output: NB=128 -> 64x64 (2x2 wave grid); NB=64 -> 32x64 (4x1).
template <int NB>
__global__ __launch_bounds__(256) void gemm_bt(const short* __restrict__ A, int lda,
                                               const short* __restrict__ Bt,
                                               float* __restrict__ Cf,
                                               short* __restrict__ Cb,
                                               int Ndim, int Kdim) {
  __shared__ short As[128 * 64];
  __shared__ short Bs[NB * 64];
  constexpr int NW = NB / 64;
  constexpr int NF = 4;                    // n-frags per wave: always 64 cols
  constexpr int MF = (NW == 2) ? 4 : 2;
  int tid = threadIdx.x;
  int w = tid >> 6, l = tid & 63;
  int lg = l >> 4, ll = l & 15;
  int wr = (NW == 2) ? (w >> 1) : w;
  int wc = (NW == 2) ? (w & 1) : 0;
  int row0 = blockIdx.y * 128, col0 = blockIdx.x * NB;

  f32x4 acc[MF][NF];
#pragma unroll
  for (int m = 0; m < MF; ++m)
#pragma unroll
    for (int n = 0; n < NF; ++n) acc[m][n] = (f32x4){0.f, 0.f, 0.f, 0.f};

  for (int k0 = 0; k0 < Kdim; k0 += 64) {
    __syncthreads();
#pragma unroll
    for (int it = 0; it < 4; ++it) {
      int s = it * 256 + w * 64 + l;
      int r = s >> 3;
      int c = (s & 7) ^ (r & 7);
      gload_lds16(A + (size_t)(row0 + r) * lda + k0 + c * 8, &As[(it * 256 + w * 64) * 8]);
    }
#pragma unroll
    for (int it = 0; it < NB / 32; ++it) {
      int s = it * 256 + w * 64 + l;
      int r = s >> 3;
      int c = (s & 7) ^ (r & 7);
      gload_lds16(Bt + (size_t)(col0 + r) * Kdim + k0 + c * 8, &Bs[(it * 256 + w * 64) * 8]);
    }
    __syncthreads();
#pragma unroll
    for (int ks = 0; ks < 2; ++ks) {
      bf16x8 af[MF], bfr[NF];
#pragma unroll
      for (int m = 0; m < MF; ++m) {
        int r = wr * (MF * 16) + m * 16 + ll;
        af[m] = *(const bf16x8*)&As[r * 64 + (((ks * 4 + lg) ^ (r & 7)) << 3)];
      }
#pragma unroll
      for (int n = 0; n < NF; ++n) {
        int r = wc * 64 + n * 16 + ll;
        bfr[n] = *(const bf16x8*)&Bs[r * 64 + (((ks * 4 + lg) ^ (r & 7)) << 3)];
      }
#pragma unroll
      for (int m = 0; m < MF; ++m)
#pragma unroll
        for (int n = 0; n < NF; ++n)
          acc[m][n] = __builtin_amdgcn_mfma_f32_16x16x32_bf16(af[m], bfr[n], acc[m][n], 0, 0, 0);
    }
  }
#pragma unroll
  for (int m = 0; m < MF; ++m) {
    int gr = row0 + wr * (MF * 16) + m * 16 + lg * 4;
#pragma unroll
    for (int n = 0; n < NF; ++n) {
      int gc = col0 + wc * 64 + n * 16 + ll;
#pragma unroll
      for (int r = 0; r < 4; ++r) {
        float vv = acc[m][n][r];
        if (Cf) Cf[(size_t)(gr + r) * Ndim + gc] = vv;
        if (Cb) Cb[(size_t)(gr + r) * Ndim + gc] = f2b(vv);
      }
    }
  }
}

// ---------------- merged QKV + KV2 GEMM (1280 blocks, XCD-chunked swizzle) ----------------
__global__ __launch_bounds__(256) void gemm_dual(const short* __restrict__ xb,
                                                 const short* __restrict__ l2b,
                                                 const short* __restrict__ wqkvT,
                                                 short* __restrict__ QKV,
                                                 short* __restrict__ KV2) {
  int lin = blockIdx.y * 40 + blockIdx.x;
  int lin2 = (lin & 7) * 160 + (lin >> 3);
  int bx = lin2 % 40;
  int by = lin2 / 40;

  const short* A;
  const short* Bt;
  short* Cb;
  int Ndim, col0;
  if (bx < 24) {
    A = xb; Bt = wqkvT; Cb = QKV; Ndim = 3072; col0 = bx * 128;
  } else {
    A = l2b; Bt = wqkvT + 1024 * 1024; Cb = KV2; Ndim = 2048; col0 = (bx - 24) * 128;
  }
  __shared__ short As[128 * 64];
  __shared__ short Bs[128 * 64];
  int tid = threadIdx.x;
  int w = tid >> 6, l = tid & 63;
  int lg = l >> 4, ll = l & 15;
  int wr = w >> 1, wc = w & 1;
  int row0 = by * 128;

  f32x4 acc[4][4];
#pragma unroll
  for (int m = 0; m < 4; ++m)
#pragma unroll
    for (int n = 0; n < 4; ++n) acc[m][n] = (f32x4){0.f, 0.f, 0.f, 0.f};

  for (int k0 = 0; k0 < 1024; k0 += 64) {
    __syncthreads();
#pragma unroll
    for (int it = 0; it < 4; ++it) {
      int s = it * 256 + w * 64 + l;
      int r = s >> 3;
      int c = (s & 7) ^ (r & 7);
      gload_lds16(A + (size_t)(row0 + r) * 1024 + k0 + c * 8, &As[(it * 256 + w * 64) * 8]);
      gload_lds16(Bt + (size_t)(col0 + r) * 1024 + k0 + c * 8, &Bs[(it * 256 + w * 64) * 8]);
    }
    __syncthreads();
#pragma unroll
    for (int ks = 0; ks < 2; ++ks) {
      bf16x8 af[4], bfr[4];
#pragma unroll
      for (int m = 0; m < 4; ++m) {
        int r = wr * 64 + m * 16 + ll;
        af[m] = *(const bf16x8*)&As[r * 64 + (((ks * 4 + lg) ^ (r & 7)) << 3)];
      }
#pragma unroll
      for (int n = 0; n < 4; ++n) {
        int r = wc * 64 + n * 16 + ll;
        bfr[n] = *(const bf16x8*)&Bs[r * 64 + (((ks * 4 + lg) ^ (r & 7)) << 3)];
      }
#pragma unroll
      for (int m = 0; m < 4; ++m)
#pragma unroll
        for (int n = 0; n < 4; ++n)
          acc[m][n] = __builtin_amdgcn_mfma_f32_16x16x32_bf16(af[m], bfr[n], acc[m][n], 0, 0, 0);
    }
  }
#pragma unroll
  for (int m = 0; m < 4; ++m) {
    int gr = row0 + wr * 64 + m * 16 + lg * 4;
#pragma unroll
    for (int n = 0; n < 4; ++n) {
      int gc = col0 + wc * 64 + n * 16 + ll;
#pragma unroll
      for (int r = 0; r < 4; ++r)
        Cb[(size_t)(gr + r) * Ndim + gc] = f2b(acc[m][n][r]);
    }
  }
}

// ---------------- v3 = l3_memory @ wv  ([B,1024], f32) ----------------
__global__ __launch_bounds__(256) void v3_kernel(const float* __restrict__ l3,
                                                 const float* __restrict__ wv,
                                                 float* __restrict__ v3) {
  int idx = blockIdx.x * 256 + threadIdx.x;  // B*D = 4096
  int b = idx >> 10;
  int col = idx & 1023;
  const float* xr = l3 + (size_t)b * D_;
  float acc = 0.f;
#pragma unroll 8
  for (int k = 0; k < D_; ++k) acc += xr[k] * wv[(size_t)k * D_ + col];
  v3[idx] = acc;
}

// ---------------- router ----------------
__global__ __launch_bounds__(256) void router_kernel(const float* __restrict__ hdnp,
                                                     const float* __restrict__ rb1,
                                                     const float* __restrict__ rw2,
                                                     const float* __restrict__ rb2,
                                                     float* __restrict__ lam) {
  int wave = (blockIdx.x * 256 + threadIdx.x) >> 6;
  int lane = threadIdx.x & 63;
  const float* hr = hdnp + (size_t)wave * 512;
  float s0 = 0.f, s1 = 0.f, s2 = 0.f;
#pragma unroll
  for (int u = 0; u < 8; ++u) {
    int hcol = u * 64 + lane;
    float vv = hr[hcol] + rb1[hcol];
    float gl = 0.5f * vv * (1.0f + erff(vv * 0.70710678118654752f));
    s0 += gl * rw2[hcol * 3 + 0];
    s1 += gl * rw2[hcol * 3 + 1];
    s2 += gl * rw2[hcol * 3 + 2];
  }
#pragma unroll
  for (int off = 32; off; off >>= 1) {
    s0 += __shfl_xor(s0, off);
    s1 += __shfl_xor(s1, off);
    s2 += __shfl_xor(s2, off);
  }
  if (lane == 0) {
    float a = s0 + rb2[0], bb = s1 + rb2[1], c = s2 + rb2[2];
    float m = fmaxf(fmaxf(a, bb), c);
    float e0 = expf(a - m), e1 = expf(bb - m), e2 = expf(c - m);
    float inv = 1.0f / (e0 + e1 + e2);
    lam[(size_t)wave * 3 + 0] = e0 * inv;
    lam[(size_t)wave * 3 + 1] = e1 * inv;
    lam[(size_t)wave * 3 + 2] = e2 * inv;
  }
}

// ---------------- fused dual-stream MFMA flash attention (R8 version) ----------------
// One block = 64 q-rows of one (b,h); 4 waves x 16 rows. KV tile 64, both
// streams. l-sum via ones-MFMA. K staged with global_load_lds (pre-swizzled
// source). Defer-max (THR=8, exp2 domain). Interior tiles skip causal mask.
__global__ __launch_bounds__(256) void attn_fused_kernel(
    const short* __restrict__ q, int ldq,
    const short* __restrict__ k1, const short* __restrict__ v1, int ld1,
    const short* __restrict__ k2, const short* __restrict__ v2, int ld2,
    const float* __restrict__ lam, const float* __restrict__ v3,
    short* __restrict__ mixedb) {
  __shared__ short Ks[2][64][64];   // [stream][key][dh], k8 XOR swizzle (linear dest)
  __shared__ short Vt[2][64][64];   // [stream][dh][key], dword XOR swizzle
  __shared__ short Ps[4][16][64];   // per-wave P, kt XOR swizzle

  int bid = blockIdx.x;
  int half = bid >> 9, p = bid & 511;
  int bh = p & 63;
  int j = p >> 6;
  int qb = half ? (15 - j) : j;
  int b = bh >> 4, h = bh & 15;
  int q0 = qb * 64;
  int tid = threadIdx.x;
  int w = tid >> 6, l = tid & 63;
  int lg = l >> 4, ll = l & 15;

  int qw0 = q0 + w * 16;
  // Q fragments straight from global (each row read exactly once)
  bf16x8 qf[2];
  {
    const short* qr = q + (size_t)(b * T_ + qw0 + ll) * ldq + h * DH_;
    qf[0] = *(const bf16x8*)&qr[lg * 8];
    qf[1] = *(const bf16x8*)&qr[32 + lg * 8];
  }

  float m_[2][4];
  f32x4 o[2][4];   // [stream][db]
  f32x4 ol[2];     // [stream] row-sum accumulator
#pragma unroll
  for (int s = 0; s < 2; ++s) {
#pragma unroll
    for (int r = 0; r < 4; ++r) m_[s][r] = -1e30f;
#pragma unroll
    for (int db = 0; db < 4; ++db) o[s][db] = (f32x4){0.f, 0.f, 0.f, 0.f};
    ol[s] = (f32x4){0.f, 0.f, 0.f, 0.f};
  }

  bf16x8 ones;
#pragma unroll
  for (int jj = 0; jj < 8; ++jj) ones[jj] = (short)0x3F80;  // 1.0bf16

  const float SC = 0.125f * 1.44269504f;  // scale * log2(e)
  int nt = qb + 1;
  for (int t64 = 0; t64 < nt; ++t64) {
    int key0 = t64 * 64;
    __syncthreads();
    // ---- stage K (global_load_lds, pre-swizzled source) and V (pack-transpose) ----
#pragma unroll
    for (int s = 0; s < 2; ++s) {
      const short* kp = s ? k2 : k1;
      const short* vp = s ? v2 : v1;
      int ld = s ? ld2 : ld1;
#pragma unroll
      for (int it = 0; it < 2; ++it) {
        int e = it * 256 + w * 64 + l;
        int r = e >> 3;
        int cs = (e & 7) ^ (r & 7);
        gload_lds16(kp + (size_t)(b * T_ + key0 + r) * ld + h * DH_ + cs * 8,
                    (short*)Ks[s] + (it * 256 + w * 64) * 8);
      }
      {
        int kp2 = tid >> 3, c8 = tid & 7;
        size_t gi = (size_t)(b * T_ + key0 + kp2 * 2) * ld + h * DH_ + c8 * 8;
        bf16x8 va = *(const bf16x8*)&vp[gi];
        bf16x8 vb = *(const bf16x8*)&vp[gi + ld];
        unsigned int* Vtd = (unsigned int*)Vt[s];
#pragma unroll
        for (int jj = 0; jj < 8; ++jj) {
          int dh = c8 * 8 + jj;
          int X = ((dh ^ (dh >> 3)) & 7) << 2;
          Vtd[dh * 32 + (kp2 ^ X)] =
              ((unsigned int)(unsigned short)va[jj]) |
              (((unsigned int)(unsigned short)vb[jj]) << 16);
        }
      }
    }
    __syncthreads();
    if (key0 > qw0 + 15) continue;  // wave fully masked (uniform per wave)

#pragma unroll
    for (int s = 0; s < 2; ++s) {
      // ---- QK^T: 8 MFMA ----
      f32x4 c[4];
#pragma unroll
      for (int kt = 0; kt < 4; ++kt) c[kt] = (f32x4){0.f, 0.f, 0.f, 0.f};
      __builtin_amdgcn_s_setprio(1);
#pragma unroll
      for (int kt = 0; kt < 4; ++kt) {
        int kr = kt * 16 + ll;
        bf16x8 kfa = *(const bf16x8*)&Ks[s][kr][((lg ^ (kr & 7)) << 3)];
        bf16x8 kfb = *(const bf16x8*)&Ks[s][kr][(((4 + lg) ^ (kr & 7)) << 3)];
        c[kt] = __builtin_amdgcn_mfma_f32_16x16x32_bf16(qf[0], kfa, c[kt], 0, 0, 0);
        c[kt] = __builtin_amdgcn_mfma_f32_16x16x32_bf16(qf[1], kfb, c[kt], 0, 0, 0);
      }
      __builtin_amdgcn_s_setprio(0);

      // ---- scores (interior tiles skip mask) ----
      float sv[4][4];
      if (key0 + 63 <= qw0) {
#pragma unroll
        for (int r = 0; r < 4; ++r)
#pragma unroll
          for (int kt = 0; kt < 4; ++kt) sv[r][kt] = c[kt][r] * SC;
      } else {
#pragma unroll
        for (int r = 0; r < 4; ++r) {
          int grow = qw0 + lg * 4 + r;
#pragma unroll
          for (int kt = 0; kt < 4; ++kt) {
            float t = c[kt][r] * SC;
            sv[r][kt] = (key0 + kt * 16 + ll > grow) ? -1e30f : t;
          }
        }
      }

      // ---- row max + defer-max rescale ----
      float mx[4];
#pragma unroll
      for (int r = 0; r < 4; ++r) {
        float m0 = fmaxf(fmaxf(sv[r][0], sv[r][1]), fmaxf(sv[r][2], sv[r][3]));
        m0 = fmaxf(m0, __shfl_xor(m0, 1));
        m0 = fmaxf(m0, __shfl_xor(m0, 2));
        m0 = fmaxf(m0, __shfl_xor(m0, 4));
        m0 = fmaxf(m0, __shfl_xor(m0, 8));
        mx[r] = m0;
      }
      int grew = 0;
#pragma unroll
      for (int r = 0; r < 4; ++r) grew |= (mx[r] > m_[s][r] + 8.f) ? 1 : 0;
      if (__any(grew)) {
#pragma unroll
        for (int r = 0; r < 4; ++r) {
          float nm = fmaxf(m_[s][r], mx[r]);
          float al = exp2f(m_[s][r] - nm);
          m_[s][r] = nm;
          ol[s][r] *= al;
#pragma unroll
          for (int db = 0; db < 4; ++db) o[s][db][r] *= al;
        }
      }

      // ---- P = exp2(sv - m), write to LDS ----
#pragma unroll
      for (int r = 0; r < 4; ++r) {
        float mr = m_[s][r];
        int prow = lg * 4 + r;
#pragma unroll
        for (int kt = 0; kt < 4; ++kt) {
          float pv = exp2f(sv[r][kt] - mr);
          Ps[w][prow][((kt ^ lg) << 4) + ll] = f2b(pv);
        }
      }
      asm volatile("s_waitcnt lgkmcnt(0)" ::: "memory");
      __builtin_amdgcn_sched_barrier(0);

      // ---- PV: 8 MFMA + 2 for row-sum ----
      __builtin_amdgcn_s_setprio(1);
#pragma unroll
      for (int ks = 0; ks < 2; ++ks) {
        int pswz = (ks * 32 + lg * 8) ^ ((ll >> 2) << 4);
        bf16x8 pf = *(const bf16x8*)&Ps[w][ll][pswz];
        const unsigned int* Vtd = (const unsigned int*)Vt[s];
        ol[s] = __builtin_amdgcn_mfma_f32_16x16x32_bf16(pf, ones, ol[s], 0, 0, 0);
#pragma unroll
        for (int db = 0; db < 4; ++db) {
          int dh = db * 16 + ll;
          int X = ((dh ^ (dh >> 3)) & 7) << 2;
          bf16x8 vf = *(const bf16x8*)&Vtd[dh * 32 + ((ks * 16 + lg * 4) ^ X)];
          o[s][db] = __builtin_amdgcn_mfma_f32_16x16x32_bf16(pf, vf, o[s][db], 0, 0, 0);
        }
      }
      __builtin_amdgcn_s_setprio(0);
      __builtin_amdgcn_sched_barrier(0);  // keep next stream's Ps writes behind PV reads
    }
  }

  // ---- epilogue: lam0*o0/l0 + lam1*o1/l1 + lam2*v3 -> bf16 mixed ----
#pragma unroll
  for (int r = 0; r < 4; ++r) {
    int grow = qw0 + lg * 4 + r;
    const float* lr = lam + (size_t)(b * T_ + grow) * 3;
    float w0 = lr[0] / ol[0][r];
    float w1 = lr[1] / ol[1][r];
    float w2 = lr[2];
#pragma unroll
    for (int db = 0; db < 4; ++db) {
      int dcol = h * DH_ + db * 16 + ll;
      float val = w0 * o[0][db][r] + w1 * o[1][db][r] + w2 * v3[(b << 10) + dcol];
      mixedb[(size_t)(b * T_ + grow) * D_ + dcol] = f2b(val);
    }
  }
}

extern "C" void kernel_launch(void* const* d_in, const int* in_sizes, int n_in,
                              void* d_out, int out_size, void* d_ws, size_t ws_size,
                              hipStream_t stream) {
  const float* x = (const float*)d_in[0];
  const float* l3m = (const float*)d_in[1];
  const float* wq = (const float*)d_in[2];
  const float* wk = (const float*)d_in[3];
  const float* wv = (const float*)d_in[4];
  const float* wo = (const float*)d_in[5];
  const float* rw1 = (const float*)d_in[6];
  const float* rb1 = (const float*)d_in[7];
  const float* rw2 = (const float*)d_in[8];
  const float* rb2 = (const float*)d_in[9];

  float* out = (float*)d_out;
  float* lam = out + (size_t)M_ * D_;  // output tail: [4096,3]

  float* ws = (float*)d_ws;
  float* l2 = ws;
  short* QKV = (short*)ws;              // [4096][3072] bf16
  float* hdnp = ws + 6291456;           // 2M floats (after 24MB R0)
  float* v3 = ws + 8388608;             // 4096
  float* gbuf = ws + 8392704;           // B*NCH*D = 262144 floats
  short* sb = (short*)(ws + 8654848);
  short* xb = sb;                       // 4M shorts
  short* l2b = sb + 4194304;            // 4M
  short* KV2 = sb + 8388608;            // 8M: [4096][2048]
  short* mixedb = sb + 16777216;        // 4M
  short* wqkvT = sb + 20971520;         // 3M: [3072][1024]
  short* woT = sb + 24117248;           // 1M
  short* rw1T = sb + 25165824;          // 512K

  dim3 blk(256);

  // weight transpose+convert (wq|wk|wv concat)
  transpose_w_kernel<<<dim3(32, 32, 5), blk, 0, stream>>>(
      wq, wk, wv, wo, rw1,
      wqkvT, wqkvT + 1024 * 1024, wqkvT + 2048 * 1024, woT, rw1T);

  // EMA l2 -> l2b (bf16), fused x->xb convert (ECH=16, NCH=64)
  ema_chunk_kernel<<<1024, blk, 0, stream>>>(x, l2, xb);
  ema_carry_kernel<<<16, blk, 0, stream>>>(l2, gbuf);
  ema_fix_kernel<<<16384, blk, 0, stream>>>(l2, gbuf, l2b);

  // [q|k1|v1] = xb @ wqkvT^T (N=3072) and [k2|v2] = l2b @ [wk|wv]^T (N=2048)
  gemm_dual<<<dim3(40, 32), blk, 0, stream>>>(xb, l2b, wqkvT, QKV, KV2);

  // router: hdnp = q @ rw1T (q strided inside QKV)
  gemm_bt<64><<<dim3(8, 32), blk, 0, stream>>>(QKV, 3072, rw1T, hdnp, (short*)nullptr, 512, 1024);
  router_kernel<<<1024, blk, 0, stream>>>(hdnp, rb1, rw2, rb2, lam);

  // l3 value vector
  v3_kernel<<<16, blk, 0, stream>>>(l3m, wv, v3);

  // fused dual-stream attention -> mixedb (bf16)
  attn_fused_kernel<<<1024, blk, 0, stream>>>(QKV, 3072,
                                              QKV + 1024, QKV + 2048, 3072,
                                              KV2, KV2 + 1024, 2048,
                                              lam, v3, mixedb);

  // out = mixedb @ woT
  gemm_bt<64><<<dim3(16, 32), blk, 0, stream>>>(mixedb, 1024, woT, out, (short*)nullptr, 1024, 1024);
}